// Round 12
// baseline (165.578 us; speedup 1.0000x reference)
//
#include <hip/hip_runtime.h>
#include <hip/hip_cooperative_groups.h>

namespace cg = cooperative_groups;

#define B_      32
#define HW_     (512 * 512)
#define NSP     100
#define NTOT    ((double)(B_ * (size_t)HW_))   // 8388608

// ================= cooperative path geometry =================
#define CCH    32                 // chunks per image
#define CNB    (CCH * B_)         // 1024 blocks = 4/CU on 256 CUs
#define CI4    (HW_ / 4 / CCH)    // 2048 int4/float4 per block
#define CIT    (CI4 / 256)        // 8 iters/thread
#define CREP   8                  // LDS bin replicas (tid&7)
#define CSTR   101
// LDS u32 pack: count [20:31], sum [0:19], FIXS=512 on 0.5*(r+f).
// Per (replica,bin): count <= 32thr*32px = 1024 < 4096; sum <= 1024*512 = 2^19 < 2^20.
#define CFIXINV (1.f / 512.f)
// chunk u64 pack: count<<44 | sum. Image-aggregated: sum <= 2^27 << 2^44. OK.
#define SUMMASK ((1ull << 44) - 1)

// ================= fallback (R9) geometry =================
#define FCH1    64
#define FNB1    (FCH1 * B_)               // 2048
#define FIT1    (HW_ / 4 / FCH1 / 256)    // 4
#define FCH2    32
#define F4PB2   (HW_ / 4 / FCH2)          // 2048
#define FIT2    (F4PB2 / 256)             // 8
#define FREP    16
#define FSTR    101
#define FFIXINV (1.f / 2048.f)

// ---------------------------------------------------------------- cooperative
__global__ __launch_bounds__(256, 4)
void mvc_coop(const float* __restrict__ rgb,
              const float* __restrict__ freq,
              const int*   __restrict__ spx,
              const int*   __restrict__ label,
              unsigned long long* __restrict__ partials, // [CNB][NSP]
              float* __restrict__ sqp,                   // [CNB]
              float* __restrict__ corrs,                 // [B_]
              float* __restrict__ out)
{
    __shared__ int4 spx_sh[CI4];              // 32 KB stash
    __shared__ union {
        unsigned bins[CREP * CSTR];           // 3232 B (phase 1)
        struct {                              // 2400 B (phase 2)
            unsigned long long ps[2 * NSP];
            float lm[NSP];
            float cr[NSP];
        } p2;
    } u;
    __shared__ float wsf[4];

    const int tid = threadIdx.x;
    const int c = blockIdx.x, b = blockIdx.y;
    const int bid = b * CCH + c;
    const bool pos = (label[b] != 0);

    const float4* r4 = (const float4*)rgb  + (size_t)b * (HW_/4) + (size_t)c * CI4;
    const float4* f4 = (const float4*)freq + (size_t)b * (HW_/4) + (size_t)c * CI4;

    // ---------------- phase 1: stream + bin + stash (writes stay small) ----
    float sq = 0.f;
    if (pos) {
        for (int i = tid; i < CREP * CSTR; i += 256) u.bins[i] = 0u;
        __syncthreads();
        const int base = (tid & (CREP - 1)) * CSTR;
        const int4* s4 = (const int4*)spx + (size_t)b * (HW_/4) + (size_t)c * CI4;
        #pragma unroll
        for (int k = 0; k < CIT; ++k) {
            const int idx = k * 256 + tid;
            float4 rv = r4[idx];
            float4 fv = f4[idx];
            int4   sv = s4[idx];
            spx_sh[idx] = sv;
            sq += rv.x * rv.x + fv.x * fv.x;
            sq += rv.y * rv.y + fv.y * fv.y;
            sq += rv.z * rv.z + fv.z * fv.z;
            sq += rv.w * rv.w + fv.w * fv.w;
            // 0.5*(r+f) * 512 = (r+f) * 256
            unsigned fx0 = (unsigned)((rv.x + fv.x) * 256.f + 0.5f);
            unsigned fx1 = (unsigned)((rv.y + fv.y) * 256.f + 0.5f);
            unsigned fx2 = (unsigned)((rv.z + fv.z) * 256.f + 0.5f);
            unsigned fx3 = (unsigned)((rv.w + fv.w) * 256.f + 0.5f);
            atomicAdd(&u.bins[base + sv.x], (1u << 20) | fx0);
            atomicAdd(&u.bins[base + sv.y], (1u << 20) | fx1);
            atomicAdd(&u.bins[base + sv.z], (1u << 20) | fx2);
            atomicAdd(&u.bins[base + sv.w], (1u << 20) | fx3);
        }
        __syncthreads();
        if (tid < NSP) {
            unsigned long long cc = 0, ss = 0;
            #pragma unroll
            for (int r = 0; r < CREP; ++r) {
                unsigned v = u.bins[r * CSTR + tid];
                cc += v >> 20;
                ss += v & 0xFFFFFu;
            }
            partials[(size_t)bid * NSP + tid] = (cc << 44) | ss;
        }
    } else {
        #pragma unroll
        for (int k = 0; k < CIT; ++k) {
            const int idx = k * 256 + tid;
            float4 rv = r4[idx];
            float4 fv = f4[idx];
            sq += rv.x * rv.x + fv.x * fv.x;
            sq += rv.y * rv.y + fv.y * fv.y;
            sq += rv.z * rv.z + fv.z * fv.z;
            sq += rv.w * rv.w + fv.w * fv.w;
        }
    }

    for (int off = 32; off > 0; off >>= 1) sq += __shfl_down(sq, off, 64);
    if ((tid & 63) == 0) wsf[tid >> 6] = sq;
    __syncthreads();
    if (tid == 0) sqp[bid] = wsf[0] + wsf[1] + wsf[2] + wsf[3];

    // Only ~0.8 MB dirty in L2 here -> cheap grid-wide fence (R7 lesson).
    cg::this_grid().sync();

    // ---------------- phase 2: aggregate + LUT + gather-from-LDS + write ---
    float4* t4 = (float4*)(out + 1) + (size_t)b * (HW_/4) + (size_t)c * CI4;

    if (pos) {
        if (tid < 2 * NSP) {
            const int bin = tid % NSP, half = tid / NSP;
            const unsigned long long* pb =
                partials + ((size_t)b * CCH + half * (CCH / 2)) * NSP + bin;
            unsigned long long acc = 0;
            #pragma unroll 4
            for (int k = 0; k < CCH / 2; ++k) acc += pb[(size_t)k * NSP];
            u.p2.ps[tid] = acc;
        }
        __syncthreads();
        if (tid < NSP) {
            unsigned long long v = u.p2.ps[tid] + u.p2.ps[tid + NSP];
            float n = (float)(v >> 44);
            float S = (float)(v & SUMMASK) * CFIXINV;
            float t = S / fmaxf(n, 1.f);
            u.p2.lm[tid] = t;
            u.p2.cr[tid] = -4.f * t * S + 2.f * n * t * t;
        }
        __syncthreads();

        #pragma unroll
        for (int k = 0; k < CIT; ++k) {
            const int idx = k * 256 + tid;
            int4 sv = spx_sh[idx];
            t4[idx] = make_float4(u.p2.lm[sv.x], u.p2.lm[sv.y],
                                  u.p2.lm[sv.z], u.p2.lm[sv.w]);
        }
        if (c == 0 && tid == 0) {
            float s = 0.f;
            for (int i = 0; i < NSP; ++i) s += u.p2.cr[i];
            corrs[b] = s;
        }
    } else {
        const float4 z = make_float4(0.f, 0.f, 0.f, 0.f);
        #pragma unroll
        for (int k = 0; k < CIT; ++k) t4[k * 256 + tid] = z;
        if (c == 0 && tid == 0) corrs[b] = 0.f;
    }
}

// ---------------------------------------------------------------- loss (tiny)
template <int NB>
__global__ void mvc_loss(const float* __restrict__ sqp,
                         const float* __restrict__ corrs,
                         float* __restrict__ out) {
    const int tid = threadIdx.x;
    double s = 0.0;
    for (int i = tid; i < NB; i += 256) s += (double)sqp[i];
    for (int off = 32; off > 0; off >>= 1) s += __shfl_down(s, off, 64);
    __shared__ double wsd[4];
    if ((tid & 63) == 0) wsd[tid >> 6] = s;
    __syncthreads();
    if (tid == 0) {
        double tot = wsd[0] + wsd[1] + wsd[2] + wsd[3];
        for (int i = 0; i < B_; ++i) tot += (double)corrs[i];
        out[0] = (float)(tot / NTOT);
    }
}

// ================================================================ fallback (R9)
__global__ void mvc_segsum_f(const float* __restrict__ rgb,
                             const float* __restrict__ freq,
                             const int*   __restrict__ spx,
                             const int*   __restrict__ label,
                             unsigned long long* __restrict__ partials,
                             float* __restrict__ sqp) {
    __shared__ unsigned bins[FREP * FSTR];
    const int tid = threadIdx.x;
    const int b = blockIdx.y;
    const int bid = b * FCH1 + blockIdx.x;
    const bool pos = (label[b] != 0);

    const float4* r4 = (const float4*)(rgb + (size_t)b * HW_) + blockIdx.x * 256 + tid;
    const float4* f4 = (const float4*)(freq + (size_t)b * HW_) + blockIdx.x * 256 + tid;

    float sq = 0.f;
    if (pos) {
        for (int i = tid; i < FREP * FSTR; i += 256) bins[i] = 0u;
        __syncthreads();
        const int base = (tid & (FREP - 1)) * FSTR;
        const int4* s4 = (const int4*)(spx + (size_t)b * HW_) + blockIdx.x * 256 + tid;
        #pragma unroll
        for (int k = 0; k < FIT1; ++k) {
            const size_t off = (size_t)k * FCH1 * 256;
            float4 rv = r4[off];
            float4 fv = f4[off];
            int4   sv = s4[off];
            sq += rv.x * rv.x + fv.x * fv.x;
            sq += rv.y * rv.y + fv.y * fv.y;
            sq += rv.z * rv.z + fv.z * fv.z;
            sq += rv.w * rv.w + fv.w * fv.w;
            unsigned fx0 = (unsigned)((rv.x + fv.x) * 1024.f + 0.5f);
            unsigned fx1 = (unsigned)((rv.y + fv.y) * 1024.f + 0.5f);
            unsigned fx2 = (unsigned)((rv.z + fv.z) * 1024.f + 0.5f);
            unsigned fx3 = (unsigned)((rv.w + fv.w) * 1024.f + 0.5f);
            atomicAdd(&bins[base + sv.x], (1u << 20) | fx0);
            atomicAdd(&bins[base + sv.y], (1u << 20) | fx1);
            atomicAdd(&bins[base + sv.z], (1u << 20) | fx2);
            atomicAdd(&bins[base + sv.w], (1u << 20) | fx3);
        }
        __syncthreads();
        for (int i = tid; i < NSP; i += 256) {
            unsigned long long cc = 0, ss = 0;
            #pragma unroll
            for (int r = 0; r < FREP; ++r) {
                unsigned v = bins[r * FSTR + i];
                cc += v >> 20;
                ss += v & 0xFFFFFu;
            }
            partials[(size_t)bid * NSP + i] = (cc << 44) | ss;
        }
    } else {
        #pragma unroll
        for (int k = 0; k < FIT1; ++k) {
            const size_t off = (size_t)k * FCH1 * 256;
            float4 rv = r4[off];
            float4 fv = f4[off];
            sq += rv.x * rv.x + fv.x * fv.x;
            sq += rv.y * rv.y + fv.y * fv.y;
            sq += rv.z * rv.z + fv.z * fv.z;
            sq += rv.w * rv.w + fv.w * fv.w;
        }
    }

    for (int off = 32; off > 0; off >>= 1) sq += __shfl_down(sq, off, 64);
    __shared__ float wsf[4];
    if ((tid & 63) == 0) wsf[tid >> 6] = sq;
    __syncthreads();
    if (tid == 0) sqp[bid] = wsf[0] + wsf[1] + wsf[2] + wsf[3];
}

__global__ void mvc_finalize_f(const int*   __restrict__ spx,
                               const int*   __restrict__ label,
                               const unsigned long long* __restrict__ partials,
                               float* __restrict__ corrs,
                               float* __restrict__ out) {
    __shared__ unsigned long long ps[2 * NSP];
    __shared__ float lm[NSP];
    __shared__ float cr[NSP];
    const int tid = threadIdx.x;
    const int c = blockIdx.x, b = blockIdx.y;
    const bool pos = (label[b] != 0);

    float4* t4 = (float4*)(out + 1) + (size_t)b * (HW_/4) + (size_t)c * F4PB2;

    if (pos) {
        if (tid < 2 * NSP) {
            const int bin = tid % NSP, half = tid / NSP;
            const unsigned long long* pb =
                partials + ((size_t)b * FCH1 + half * (FCH1 / 2)) * NSP + bin;
            unsigned long long acc = 0;
            #pragma unroll 4
            for (int k = 0; k < FCH1 / 2; ++k) acc += pb[(size_t)k * NSP];
            ps[tid] = acc;
        }
        __syncthreads();
        if (tid < NSP) {
            unsigned long long v = ps[tid] + ps[tid + NSP];
            float n = (float)(v >> 44);
            float S = (float)(v & SUMMASK) * FFIXINV;
            float t = S / fmaxf(n, 1.f);
            lm[tid] = t;
            cr[tid] = -4.f * t * S + 2.f * n * t * t;
        }
        __syncthreads();

        const int4* s4 = (const int4*)spx + (size_t)b * (HW_/4) + (size_t)c * F4PB2;
        #pragma unroll
        for (int k = 0; k < FIT2; ++k) {
            const int idx = k * 256 + tid;
            int4 sv = s4[idx];
            t4[idx] = make_float4(lm[sv.x], lm[sv.y], lm[sv.z], lm[sv.w]);
        }
        if (c == 0 && tid == 0) {
            float s = 0.f;
            for (int i = 0; i < NSP; ++i) s += cr[i];
            corrs[b] = s;
        }
    } else {
        const float4 z = make_float4(0.f, 0.f, 0.f, 0.f);
        #pragma unroll
        for (int k = 0; k < FIT2; ++k) t4[k * 256 + tid] = z;
        if (c == 0 && tid == 0) corrs[b] = 0.f;
    }
}

// ---------------------------------------------------------------- launch
extern "C" void kernel_launch(void* const* d_in, const int* in_sizes, int n_in,
                              void* d_out, int out_size, void* d_ws, size_t ws_size,
                              hipStream_t stream) {
    const float* rgb   = (const float*)d_in[0];
    const float* freq  = (const float*)d_in[1];
    const int*   label = (const int*)d_in[2];
    const int*   spx   = (const int*)d_in[3];
    float* out = (float*)d_out;

    // Overlapping regions: exactly one path runs.
    unsigned long long* partials = (unsigned long long*)d_ws;        // <=1.6 MB
    float* sqp_c   = (float*)(partials + (size_t)CNB * NSP);         // coop: after 800KB
    float* corrs_c = sqp_c + CNB;
    float* sqp_f   = (float*)(partials + (size_t)FNB1 * NSP);        // fallback: after 1.6MB
    float* corrs_f = sqp_f + FNB1;

    void* args[] = { (void*)&rgb, (void*)&freq, (void*)&spx, (void*)&label,
                     (void*)&partials, (void*)&sqp_c, (void*)&corrs_c,
                     (void*)&out };
    hipError_t err = hipLaunchCooperativeKernel((const void*)mvc_coop,
                                                dim3(CCH, B_), dim3(256),
                                                args, 0, stream);
    if (err == hipSuccess) {
        mvc_loss<CNB><<<1, 256, 0, stream>>>(sqp_c, corrs_c, out);
    } else {
        // proven R9 path
        mvc_segsum_f<<<dim3(FCH1, B_), 256, 0, stream>>>(rgb, freq, spx, label,
                                                         partials, sqp_f);
        mvc_finalize_f<<<dim3(FCH2, B_), 256, 0, stream>>>(spx, label, partials,
                                                           corrs_f, out);
        mvc_loss<FNB1><<<1, 256, 0, stream>>>(sqp_f, corrs_f, out);
    }
}

// Round 13
// 32.714 us; speedup vs baseline: 5.0613x; 5.0613x over previous
//
#include <hip/hip_runtime.h>

#define B_      32
#define HW_     (512 * 512)
#define NSP     100
#define NTOT    ((double)(B_ * (size_t)HW_))   // 8388608

// --- K1 geometry ---
#define CHUNKS1 64
#define NBLK1   (CHUNKS1 * B_)              // 2048 blocks, 8/CU
#define ITERS1  (HW_ / 4 / CHUNKS1 / 256)   // 4 int4 per thread
// --- K2 geometry ---
#define CHUNKS2 32
#define F4PB2   (HW_ / 4 / CHUNKS2)         // 2048 int4/float4 per block
#define ITERS2  (F4PB2 / 256)               // 8

#define REP      16     // LDS bin replicas (tid&15): 16 threads x 16 px = 256 px max each
#define RSTRIDE  101    // u32 stride between replicas
// LDS u32 pack: count in [20:31], sum in [0:19] at 2^11 fixed point (of 0.5*(r+f)).
// Per (replica,bin): count <= 256, sum <= 256*2049 < 2^20. No carry.
#define FIXINV  (1.f / 2048.f)
// per-chunk u64 pack: count << 44 | sum. Aggregated over 64 chunks:
// count <= 2^18, sum <= 2^27 << 2^44 -> no field carry.
#define SUMMASK ((1ull << 44) - 1)

// ---------------------------------------------------------------- K1
// grid = (CHUNKS1, B), 256 threads. Positive-label images: LDS u32 bins ->
// per-chunk partials STORED. Negative-label images: pure sq-sum stream
// (no spx read, no binning, no partials). Branch is block-uniform.
__global__ void mvc_segsum(const float* __restrict__ rgb,
                           const float* __restrict__ freq,
                           const int*   __restrict__ spx,
                           const int*   __restrict__ label,
                           unsigned long long* __restrict__ partials, // [NBLK1][NSP]
                           float* __restrict__ sqp) {                 // [NBLK1]
    __shared__ unsigned bins[REP * RSTRIDE];
    const int tid = threadIdx.x;
    const int b = blockIdx.y;
    const int bid = b * CHUNKS1 + blockIdx.x;
    const bool pos = (label[b] != 0);

    const float4* r4 = (const float4*)(rgb + (size_t)b * HW_) + blockIdx.x * 256 + tid;
    const float4* f4 = (const float4*)(freq + (size_t)b * HW_) + blockIdx.x * 256 + tid;

    float sq = 0.f;
    if (pos) {
        for (int i = tid; i < REP * RSTRIDE; i += 256) bins[i] = 0u;
        __syncthreads();
        const int base = (tid & (REP - 1)) * RSTRIDE;
        const int4* s4 = (const int4*)(spx + (size_t)b * HW_) + blockIdx.x * 256 + tid;
        #pragma unroll
        for (int k = 0; k < ITERS1; ++k) {
            const size_t off = (size_t)k * CHUNKS1 * 256;
            float4 rv = r4[off];
            float4 fv = f4[off];
            int4   sv = s4[off];
            sq += rv.x * rv.x + fv.x * fv.x;
            sq += rv.y * rv.y + fv.y * fv.y;
            sq += rv.z * rv.z + fv.z * fv.z;
            sq += rv.w * rv.w + fv.w * fv.w;
            // 0.5*(r+f) * 2^11 = (r+f) * 1024
            unsigned fx0 = (unsigned)((rv.x + fv.x) * 1024.f + 0.5f);
            unsigned fx1 = (unsigned)((rv.y + fv.y) * 1024.f + 0.5f);
            unsigned fx2 = (unsigned)((rv.z + fv.z) * 1024.f + 0.5f);
            unsigned fx3 = (unsigned)((rv.w + fv.w) * 1024.f + 0.5f);
            atomicAdd(&bins[base + sv.x], (1u << 20) | fx0);
            atomicAdd(&bins[base + sv.y], (1u << 20) | fx1);
            atomicAdd(&bins[base + sv.z], (1u << 20) | fx2);
            atomicAdd(&bins[base + sv.w], (1u << 20) | fx3);
        }
        __syncthreads();
        for (int i = tid; i < NSP; i += 256) {
            unsigned long long cc = 0, ss = 0;
            #pragma unroll
            for (int r = 0; r < REP; ++r) {
                unsigned v = bins[r * RSTRIDE + i];
                cc += v >> 20;
                ss += v & 0xFFFFFu;
            }
            partials[(size_t)bid * NSP + i] = (cc << 44) | ss;
        }
    } else {
        #pragma unroll
        for (int k = 0; k < ITERS1; ++k) {
            const size_t off = (size_t)k * CHUNKS1 * 256;
            float4 rv = r4[off];
            float4 fv = f4[off];
            sq += rv.x * rv.x + fv.x * fv.x;
            sq += rv.y * rv.y + fv.y * fv.y;
            sq += rv.z * rv.z + fv.z * fv.z;
            sq += rv.w * rv.w + fv.w * fv.w;
        }
    }

    for (int off = 32; off > 0; off >>= 1) sq += __shfl_down(sq, off, 64);
    __shared__ float wsf[4];
    if ((tid & 63) == 0) wsf[tid >> 6] = sq;
    __syncthreads();
    if (tid == 0) sqp[bid] = wsf[0] + wsf[1] + wsf[2] + wsf[3];
}

// ---------------------------------------------------------------- K2
// grid = (CHUNKS2, B), 256 threads. Positive images: aggregate the image's
// 64 chunk-partials (L2/L3), build mean LUT, gather spx, write tgt map.
// Negative images: zero-fill tgt. c==0 blocks emit the corr term.
__global__ void mvc_finalize(const int*   __restrict__ spx,
                             const int*   __restrict__ label,
                             const unsigned long long* __restrict__ partials,
                             float* __restrict__ corrs,   // [B_]
                             float* __restrict__ out) {
    __shared__ unsigned long long ps[2 * NSP];
    __shared__ float lm[NSP];
    __shared__ float cr[NSP];
    const int tid = threadIdx.x;
    const int c = blockIdx.x, b = blockIdx.y;
    const bool pos = (label[b] != 0);

    float4* t4 = (float4*)(out + 1) + (size_t)b * (HW_/4) + (size_t)c * F4PB2;

    if (pos) {
        if (tid < 2 * NSP) {
            const int bin = tid % NSP, half = tid / NSP;
            const unsigned long long* pb =
                partials + ((size_t)b * CHUNKS1 + half * (CHUNKS1 / 2)) * NSP + bin;
            unsigned long long acc = 0;
            #pragma unroll 4
            for (int k = 0; k < CHUNKS1 / 2; ++k) acc += pb[(size_t)k * NSP];
            ps[tid] = acc;
        }
        __syncthreads();
        if (tid < NSP) {
            unsigned long long v = ps[tid] + ps[tid + NSP];
            float n = (float)(v >> 44);
            float S = (float)(v & SUMMASK) * FIXINV;
            float t = S / fmaxf(n, 1.f);
            lm[tid] = t;
            cr[tid] = -4.f * t * S + 2.f * n * t * t;
        }
        __syncthreads();

        const int4* s4 = (const int4*)spx + (size_t)b * (HW_/4) + (size_t)c * F4PB2;
        #pragma unroll
        for (int k = 0; k < ITERS2; ++k) {
            const int idx = k * 256 + tid;
            int4 sv = s4[idx];
            t4[idx] = make_float4(lm[sv.x], lm[sv.y], lm[sv.z], lm[sv.w]);
        }

        if (c == 0 && tid == 0) {
            float s = 0.f;
            for (int i = 0; i < NSP; ++i) s += cr[i];
            corrs[b] = s;
        }
    } else {
        const float4 z = make_float4(0.f, 0.f, 0.f, 0.f);
        #pragma unroll
        for (int k = 0; k < ITERS2; ++k)
            t4[k * 256 + tid] = z;
        if (c == 0 && tid == 0) corrs[b] = 0.f;
    }
}

// ---------------------------------------------------------------- K3
// 1 block. Deterministic fixed-order f64 reduction of sq-partials + corrs.
__global__ void mvc_loss(const float* __restrict__ sqp,
                         const float* __restrict__ corrs,
                         float* __restrict__ out) {
    const int tid = threadIdx.x;
    double s = 0.0;
    for (int i = tid; i < NBLK1; i += 256) s += (double)sqp[i];
    for (int off = 32; off > 0; off >>= 1) s += __shfl_down(s, off, 64);
    __shared__ double wsd[4];
    if ((tid & 63) == 0) wsd[tid >> 6] = s;
    __syncthreads();
    if (tid == 0) {
        double tot = wsd[0] + wsd[1] + wsd[2] + wsd[3];
        for (int i = 0; i < B_; ++i) tot += (double)corrs[i];
        out[0] = (float)(tot / NTOT);
    }
}

// ---------------------------------------------------------------- launch
extern "C" void kernel_launch(void* const* d_in, const int* in_sizes, int n_in,
                              void* d_out, int out_size, void* d_ws, size_t ws_size,
                              hipStream_t stream) {
    const float* rgb   = (const float*)d_in[0];
    const float* freq  = (const float*)d_in[1];
    const int*   label = (const int*)d_in[2];
    const int*   spx   = (const int*)d_in[3];
    float* out = (float*)d_out;

    unsigned long long* partials = (unsigned long long*)d_ws;     // 1.6 MB
    float* sqp   = (float*)(partials + (size_t)NBLK1 * NSP);      // 8 KB
    float* corrs = sqp + NBLK1;                                   // 128 B

    mvc_segsum<<<dim3(CHUNKS1, B_), 256, 0, stream>>>(rgb, freq, spx, label,
                                                      partials, sqp);
    mvc_finalize<<<dim3(CHUNKS2, B_), 256, 0, stream>>>(spx, label, partials,
                                                        corrs, out);
    mvc_loss<<<1, 256, 0, stream>>>(sqp, corrs, out);
}